// Round 9
// baseline (80.998 us; speedup 1.0000x reference)
//
#include <hip/hip_runtime.h>

// x:(32,1,512,512) f32, theta:(4,) f32
// out flat (reference raw .view): out_flat[l*128 + b*4 + q] -> float4 units out4[l*32+b]
// Closed form of the 4-qubit circuit (CNOT ring is GF(2)-linear; RY orthogonal):
//   <Z_q> = cos(theta_q)*prod_{S_q} cos(a_r) - sin(theta_q)*prod_{T_q} sin(a_r)
//   S0={1,2,3} S1={0,1} S2={0,1,2} S3={0,1,2,3};  T0={0,1} T1={1,2} T2={2,3} T3={0,1,3}
#define HH 512
#define WW 512
#define HO 256
#define WO 256
#define LTOT (HO * WO)

// hardware v_sin/v_cos take revolutions: sin(a) = v_sin(a/(2pi)); |a|<~6 -> in range
#define INV_2PI 0.15915494309189535f

typedef float f4 __attribute__((ext_vector_type(4)));  // native vector: nontemporal-ok

__device__ __forceinline__ f4 qnode(float a0, float a1, float a2, float a3,
                                    const float* __restrict__ ct,
                                    const float* __restrict__ st) {
    float ca[4], sa[4];
    const float r0 = a0 * INV_2PI, r1 = a1 * INV_2PI, r2 = a2 * INV_2PI, r3 = a3 * INV_2PI;
    sa[0] = __builtin_amdgcn_sinf(r0); ca[0] = __builtin_amdgcn_cosf(r0);
    sa[1] = __builtin_amdgcn_sinf(r1); ca[1] = __builtin_amdgcn_cosf(r1);
    sa[2] = __builtin_amdgcn_sinf(r2); ca[2] = __builtin_amdgcn_cosf(r2);
    sa[3] = __builtin_amdgcn_sinf(r3); ca[3] = __builtin_amdgcn_cosf(r3);
    const float A1 = ca[0] * ca[1];
    const float A2 = A1 * ca[2];
    const float A3 = A2 * ca[3];
    const float A0 = (ca[1] * ca[2]) * ca[3];
    const float B0 = sa[0] * sa[1];
    const float B1 = sa[1] * sa[2];
    const float B2 = sa[2] * sa[3];
    const float B3 = B0 * sa[3];
    f4 z;
    z.x = ct[0] * A0 - st[0] * B0;
    z.y = ct[1] * A1 - st[1] * B1;
    z.z = ct[2] * A2 - st[2] * B2;
    z.w = ct[3] * A3 - st[3] * B3;
    return z;
}

__global__ __launch_bounds__(256) void quanv_kernel(const float* __restrict__ x,
                                                    const float* __restrict__ theta,
                                                    float* __restrict__ out) {
    __shared__ f4 ldsA[1024];   // tile 0 staging (16 KB)
    __shared__ f4 ldsB[1024];   // tile 1 staging (16 KB)

    const int tid   = threadIdx.x;
    const int l0    = blockIdx.x * 64;   // 64 consecutive patches, same image row
    const int irow  = l0 >> 8;
    const int j0    = l0 & 255;
    const int lpair = tid & 15;          // patch-pair within tile
    const int b0    = tid >> 4;          // 0..15 -> images b0, b0+16

    float ct[4], st[4];
#pragma unroll
    for (int q = 0; q < 4; ++q) {
        const float r = theta[q] * INV_2PI;
        st[q] = __builtin_amdgcn_sinf(r);
        ct[q] = __builtin_amdgcn_cosf(r);
    }

    const int colT0 = 2 * (j0 + 2 * lpair);   // 16B-aligned
    const int colT1 = colT0 + 64;             // tile 1 = patches +32
    const int r0off = (2 * irow) * WW;
    const int r1off = r0off + WW;
    const float* xb0 = x + (size_t)b0 * (HH * WW);
    const float* xb1 = x + (size_t)(b0 + 16) * (HH * WW);

    // Issue ALL 8 loads up-front: 2 tiles x 2 images x 2 rows (128 B/thread in flight)
    const f4 t0r0a = *(const f4*)(xb0 + r0off + colT0);
    const f4 t0r1a = *(const f4*)(xb0 + r1off + colT0);
    const f4 t0r0b = *(const f4*)(xb1 + r0off + colT0);
    const f4 t0r1b = *(const f4*)(xb1 + r1off + colT0);
    const f4 t1r0a = *(const f4*)(xb0 + r0off + colT1);
    const f4 t1r1a = *(const f4*)(xb0 + r1off + colT1);
    const f4 t1r0b = *(const f4*)(xb1 + r0off + colT1);
    const f4 t1r1b = *(const f4*)(xb1 + r1off + colT1);

    // ---------- tile 0: compute -> LDS-A ----------
#pragma unroll
    for (int w = 0; w < 2; ++w) {
        const int b = b0 + 16 * w;
        const f4 r0 = w ? t0r0b : t0r0a;
        const f4 r1 = w ? t0r1b : t0r1a;
#pragma unroll
        for (int c = 0; c < 2; ++c) {
            const f4 z = qnode(c ? r0.z : r0.x, c ? r0.w : r0.y,
                               c ? r1.z : r1.x, c ? r1.w : r1.y, ct, st);
            const int lsub = 2 * lpair + c;
            ldsA[lsub * 32 + (b ^ (lsub & 31))] = z;
        }
    }
    __syncthreads();

    // tile 0 store: contiguous 16 KB span, nontemporal
    {
        f4* o = (f4*)out + (size_t)l0 * 32;
#pragma unroll
        for (int k = 0; k < 4; ++k) {
            const int idx = k * 256 + tid;
            const int ls = idx >> 5, bb = idx & 31;
            __builtin_nontemporal_store(ldsA[ls * 32 + (bb ^ (ls & 31))], &o[idx]);
        }
    }

    // ---------- tile 1: compute -> LDS-B (data already in regs) ----------
#pragma unroll
    for (int w = 0; w < 2; ++w) {
        const int b = b0 + 16 * w;
        const f4 r0 = w ? t1r0b : t1r0a;
        const f4 r1 = w ? t1r1b : t1r1a;
#pragma unroll
        for (int c = 0; c < 2; ++c) {
            const f4 z = qnode(c ? r0.z : r0.x, c ? r0.w : r0.y,
                               c ? r1.z : r1.x, c ? r1.w : r1.y, ct, st);
            const int lsub = 2 * lpair + c;
            ldsB[lsub * 32 + (b ^ (lsub & 31))] = z;
        }
    }
    __syncthreads();

    // tile 1 store: next contiguous 16 KB span
    {
        f4* o = (f4*)out + (size_t)(l0 + 32) * 32;
#pragma unroll
        for (int k = 0; k < 4; ++k) {
            const int idx = k * 256 + tid;
            const int ls = idx >> 5, bb = idx & 31;
            __builtin_nontemporal_store(ldsB[ls * 32 + (bb ^ (ls & 31))], &o[idx]);
        }
    }
}

extern "C" void kernel_launch(void* const* d_in, const int* in_sizes, int n_in,
                              void* d_out, int out_size, void* d_ws, size_t ws_size,
                              hipStream_t stream) {
    const float* x     = (const float*)d_in[0];
    const float* theta = (const float*)d_in[1];
    float* out         = (float*)d_out;

    const int blocks = LTOT / 64; // 1024 blocks = 4/CU, 2 tiles each, all co-resident
    quanv_kernel<<<blocks, 256, 0, stream>>>(x, theta, out);
}

// Round 12
// 80.964 us; speedup vs baseline: 1.0004x; 1.0004x over previous
//
#include <hip/hip_runtime.h>

// x:(32,1,512,512) f32, theta:(4,) f32
// out flat (reference raw .view): out_flat[l*128 + b*4 + q] -> float4 units out4[l*32+b]
// Closed form of the 4-qubit circuit (CNOT ring is GF(2)-linear; RY orthogonal):
//   <Z_q> = cos(theta_q)*prod_{S_q} cos(a_r) - sin(theta_q)*prod_{T_q} sin(a_r)
//   S0={1,2,3} S1={0,1} S2={0,1,2} S3={0,1,2,3};  T0={0,1} T1={1,2} T2={2,3} T3={0,1,3}
#define HH 512
#define WW 512
#define HO 256
#define WO 256
#define LTOT (HO * WO)

// hardware v_sin/v_cos take revolutions: sin(a) = v_sin(a/(2pi)); |a|<~6 -> in range
#define INV_2PI 0.15915494309189535f

typedef float f4 __attribute__((ext_vector_type(4)));

__device__ __forceinline__ f4 qnode(float a0, float a1, float a2, float a3,
                                    const float* __restrict__ ct,
                                    const float* __restrict__ st) {
    float ca[4], sa[4];
    const float r0 = a0 * INV_2PI, r1 = a1 * INV_2PI, r2 = a2 * INV_2PI, r3 = a3 * INV_2PI;
    sa[0] = __builtin_amdgcn_sinf(r0); ca[0] = __builtin_amdgcn_cosf(r0);
    sa[1] = __builtin_amdgcn_sinf(r1); ca[1] = __builtin_amdgcn_cosf(r1);
    sa[2] = __builtin_amdgcn_sinf(r2); ca[2] = __builtin_amdgcn_cosf(r2);
    sa[3] = __builtin_amdgcn_sinf(r3); ca[3] = __builtin_amdgcn_cosf(r3);
    const float A1 = ca[0] * ca[1];
    const float A2 = A1 * ca[2];
    const float A3 = A2 * ca[3];
    const float A0 = (ca[1] * ca[2]) * ca[3];
    const float B0 = sa[0] * sa[1];
    const float B1 = sa[1] * sa[2];
    const float B2 = sa[2] * sa[3];
    const float B3 = B0 * sa[3];
    f4 z;
    z.x = ct[0] * A0 - st[0] * B0;
    z.y = ct[1] * A1 - st[1] * B1;
    z.z = ct[2] * A2 - st[2] * B2;
    z.w = ct[3] * A3 - st[3] * B3;
    return z;
}

// 128-thread blocks, 16-patch x 32-batch tiles, 8 KB LDS:
// 16 blocks/CU x 2 waves = 32 waves/CU (100% occupancy cap); min-waves=8 pins VGPR<=64.
__global__ __launch_bounds__(128, 8) void quanv_kernel(const float* __restrict__ x,
                                                       const float* __restrict__ theta,
                                                       float* __restrict__ out) {
    __shared__ f4 lds[512];   // 16 patches x 32 batches (8 KB)

    const int tid   = threadIdx.x;       // 0..127
    const int l0    = blockIdx.x * 16;   // 16 consecutive patches, same image row
    const int irow  = l0 >> 8;
    const int j0    = l0 & 255;
    const int lpair = tid & 7;           // patch-pair -> patches 2*lpair, 2*lpair+1
    const int b0    = tid >> 3;          // 0..15 -> images b0, b0+16

    float ct[4], st[4];
#pragma unroll
    for (int q = 0; q < 4; ++q) {
        const float r = theta[q] * INV_2PI;
        st[q] = __builtin_amdgcn_sinf(r);
        ct[q] = __builtin_amdgcn_cosf(r);
    }

    const int col  = 2 * (j0 + 2 * lpair);   // 16B aligned
    const int off0 = (2 * irow) * WW + col;  // row 2i
    const int off1 = off0 + WW;              // row 2i+1
    const float* xb0 = x + (size_t)b0 * (HH * WW);
    const float* xb1 = x + (size_t)(b0 + 16) * (HH * WW);

    // all 4 loads issued up-front (64 B/thread in flight)
    const f4 r0a = *(const f4*)(xb0 + off0);
    const f4 r1a = *(const f4*)(xb0 + off1);
    const f4 r0b = *(const f4*)(xb1 + off0);
    const f4 r1b = *(const f4*)(xb1 + off1);

#pragma unroll
    for (int w = 0; w < 2; ++w) {
        const int b = b0 + 16 * w;
        const f4 r0 = w ? r0b : r0a;
        const f4 r1 = w ? r1b : r1a;
#pragma unroll
        for (int c = 0; c < 2; ++c) {
            const f4 z = qnode(c ? r0.z : r0.x, c ? r0.w : r0.y,
                               c ? r1.z : r1.x, c ? r1.w : r1.y, ct, st);
            const int lsub = 2 * lpair + c;                 // 0..15
            lds[lsub * 32 + (b ^ lsub)] = z;                // XOR swizzle (lsub<16<=31)
        }
    }
    __syncthreads();

    // contiguous 8 KB output span per block, nontemporal
    f4* o = (f4*)out + (size_t)l0 * 32;
#pragma unroll
    for (int k = 0; k < 4; ++k) {
        const int idx = k * 128 + tid;          // 0..511
        const int ls = idx >> 5, bb = idx & 31;
        __builtin_nontemporal_store(lds[ls * 32 + (bb ^ ls)], &o[idx]);
    }
}

extern "C" void kernel_launch(void* const* d_in, const int* in_sizes, int n_in,
                              void* d_out, int out_size, void* d_ws, size_t ws_size,
                              hipStream_t stream) {
    const float* x     = (const float*)d_in[0];
    const float* theta = (const float*)d_in[1];
    float* out         = (float*)d_out;

    const int blocks = LTOT / 16; // 4096 blocks = 16/CU queued
    quanv_kernel<<<blocks, 128, 0, stream>>>(x, theta, out);
}